// Round 6
// baseline (130.470 us; speedup 1.0000x reference)
//
#include <hip/hip_runtime.h>

// LinearGaussianTree, MI355X. 8192 rows; per row a 4095-node binary tree:
// s_i = w_i * s_parent + (1-w_i)*SCALE*noise_i. Outputs fp32 flat:
// samples (8192x4095), ms (8192x4094), scales (8192x4094), reverse level
// order; root = samples col 4094. Node t (rest-index) at level d has output
// column c = t + 4098 - 3*2^d; children (rest-idx) = 2t+2, 2t+3.
//
// r6: two barrier-free kernels split at the level-7 boundary.
//  A (lgt_top): root + levels 1..7, one WAVE per row, __shfl parent
//    broadcast. No LDS, no barriers. Level-7 samples (cols 3840..3967) are
//    part of the samples output -> serve as the handoff to B.
//  B (lgt_bulk): levels 8..11, one thread per level-8 subtree (15 nodes),
//    fully independent: copy-like streaming, zero sync. Sigmoid inline.

constexpr int   kRows  = 8192;
constexpr float kScale = 0.1f;

typedef float f4_ __attribute__((ext_vector_type(4)));
typedef float f2_ __attribute__((ext_vector_type(2)));
typedef f4_ f4u __attribute__((aligned(4)));   // 16B vector, 4B-aligned ok
typedef f2_ f2u __attribute__((aligned(4)));

__device__ __forceinline__ float sigm(float x) {
    return 1.0f / (1.0f + __expf(-x));
}

// ---- kernel A: root + levels 1..7 (one wave per row) ----
__global__ __launch_bounds__(256) void lgt_top(
    const float* __restrict__ weights,
    const float* __restrict__ noise_root,
    const float* __restrict__ noise_rest,
    float* __restrict__ samples,
    float* __restrict__ ms,
    float* __restrict__ scales)
{
    const int lane = threadIdx.x & 63;
    const int row  = (blockIdx.x << 2) + (threadIdx.x >> 6);
    const float* __restrict__ nr = noise_rest + (size_t)row * 4094;
    float* __restrict__ sr = samples + (size_t)row * 4095;
    float* __restrict__ mr = ms      + (size_t)row * 4094;
    float* __restrict__ cr = scales  + (size_t)row * 4094;

    const float rootv = noise_root[row];         // IN_SCALE == 1.0
    if (lane == 0) sr[4094] = rootv;

    // levels 1..6: level d node-local i lives on lane i (loads in-bounds for
    // all lanes: off+63 <= 125; values on lanes >= n are garbage but unused).
    float v = rootv;
    #pragma unroll
    for (int d = 1; d <= 6; ++d) {
        const int off     = (1 << d) - 2;
        const int n       = 1 << d;
        const int colbase = 4096 - (n << 1);
        const float p  = (d == 1) ? rootv : __shfl(v, lane >> 1);
        const float wt = weights[off + lane];
        const float nz = nr[off + lane];
        const float w  = sigm(wt);
        const float sc = (1.0f - w) * kScale;
        const float m  = w * p;
        v = fmaf(sc, nz, m);
        if (lane < n) {
            const int c = colbase + lane;
            sr[c] = v; mr[c] = m; cr[c] = sc;
        }
    }

    // level 7: nodes 126+2l, 127+2l; parent = own lane's level-6 value.
    {
        const f2_ wt = *(const f2_*)(weights + 126 + 2 * lane);
        const f2_ nz = *(const f2_*)(nr + 126 + 2 * lane);
        const float w0  = sigm(wt.x), w1 = sigm(wt.y);
        const float sc0 = (1.0f - w0) * kScale, sc1 = (1.0f - w1) * kScale;
        const float m0  = w0 * v, m1 = w1 * v;
        const float v0  = fmaf(sc0, nz.x, m0), v1 = fmaf(sc1, nz.y, m1);
        const int   c   = 3840 + 2 * lane;
        f2_ sv; sv.x = v0;  sv.y = v1;
        f2_ mv; mv.x = m0;  mv.y = m1;
        f2_ cv; cv.x = sc0; cv.y = sc1;
        *(f2u*)(sr + c) = sv;      // samples row base only 4B-aligned
        *(f2_*)(mr + c) = mv;      // row*4094 + c even -> 8B-aligned
        *(f2_*)(cr + c) = cv;
    }
}

// ---- kernel B: levels 8..11, one thread per level-8 subtree ----
__global__ __launch_bounds__(256) void lgt_bulk(
    const float* __restrict__ weights,
    const float* __restrict__ noise_rest,
    float*  samples,                 // read (cols 3840+) + write (cols <3840)
    float* __restrict__ ms,
    float* __restrict__ scales)
{
    const int row = blockIdx.x;
    const int s   = threadIdx.x;     // level-8 node-local index, 0..255
    const float* __restrict__ nr = noise_rest + (size_t)row * 4094;
    float* sr = samples + (size_t)row * 4095;
    float* __restrict__ mr = ms     + (size_t)row * 4094;
    float* __restrict__ cr = scales + (size_t)row * 4094;

    // level-7 ancestor (written by lgt_top into the samples output)
    const float a7 = sr[3840 + (s >> 1)];

    // ---- loads: weights (tree-index) and noise, all contiguous per level --
    const float w8t = weights[254 + s];
    const f2_  w9t  = *(const f2_*)(weights + 510  + 2 * s);
    const f2_  wA0  = *(const f2_*)(weights + 1022 + 4 * s);
    const f2_  wA1  = *(const f2_*)(weights + 1022 + 4 * s + 2);
    f2_ wB[4];
    #pragma unroll
    for (int k = 0; k < 4; ++k)
        wB[k] = *(const f2_*)(weights + 2046 + 8 * s + 2 * k);

    const float n8 = nr[254 + s];
    const f2_  n9  = *(const f2_*)(nr + 510  + 2 * s);
    const f2_  nA0 = *(const f2_*)(nr + 1022 + 4 * s);
    const f2_  nA1 = *(const f2_*)(nr + 1022 + 4 * s + 2);
    f2_ nB[4];
    #pragma unroll
    for (int k = 0; k < 4; ++k)
        nB[k] = *(const f2_*)(nr + 2046 + 8 * s + 2 * k);

    // ---- level 8: col 3584+s ----
    const float w8  = sigm(w8t);
    const float c8  = (1.0f - w8) * kScale;
    const float m8  = w8 * a7;
    const float v8  = fmaf(c8, n8, m8);
    sr[3584 + s] = v8; mr[3584 + s] = m8; cr[3584 + s] = c8;

    // ---- level 9: cols 3072+2s (contiguous 2) ----
    const float w90 = sigm(w9t.x), w91 = sigm(w9t.y);
    const float c90 = (1.0f - w90) * kScale, c91 = (1.0f - w91) * kScale;
    const float m90 = w90 * v8, m91 = w91 * v8;
    const float v90 = fmaf(c90, n9.x, m90);
    const float v91 = fmaf(c91, n9.y, m91);
    {
        f2_ sv; sv.x = v90; sv.y = v91;
        f2_ mv; mv.x = m90; mv.y = m91;
        f2_ cv; cv.x = c90; cv.y = c91;
        *(f2u*)(sr + 3072 + 2 * s) = sv;
        *(f2_*)(mr + 3072 + 2 * s) = mv;
        *(f2_*)(cr + 3072 + 2 * s) = cv;
    }

    // ---- level 10: cols 2048+4s (contiguous 4) ----
    const float wa0 = sigm(wA0.x), wa1 = sigm(wA0.y);
    const float wa2 = sigm(wA1.x), wa3 = sigm(wA1.y);
    const float ca0 = (1.0f - wa0) * kScale, ca1 = (1.0f - wa1) * kScale;
    const float ca2 = (1.0f - wa2) * kScale, ca3 = (1.0f - wa3) * kScale;
    const float mA0 = wa0 * v90, mA1 = wa1 * v90;
    const float mA2 = wa2 * v91, mA3 = wa3 * v91;
    const float vA0 = fmaf(ca0, nA0.x, mA0);
    const float vA1 = fmaf(ca1, nA0.y, mA1);
    const float vA2 = fmaf(ca2, nA1.x, mA2);
    const float vA3 = fmaf(ca3, nA1.y, mA3);
    {
        f4_ sv; sv.x = vA0; sv.y = vA1; sv.z = vA2; sv.w = vA3;
        f4_ mv; mv.x = mA0; mv.y = mA1; mv.z = mA2; mv.w = mA3;
        f4_ cv; cv.x = ca0; cv.y = ca1; cv.z = ca2; cv.w = ca3;
        *(f4u*)(sr + 2048 + 4 * s) = sv;
        *(f4u*)(mr + 2048 + 4 * s) = mv;
        *(f4u*)(cr + 2048 + 4 * s) = cv;
    }

    // ---- level 11: cols 8s (contiguous 8) ----
    const float pv[4] = { vA0, vA1, vA2, vA3 };
    float sv[8], mv[8], cv[8];
    #pragma unroll
    for (int k = 0; k < 4; ++k) {
        const float wb0 = sigm(wB[k].x), wb1 = sigm(wB[k].y);
        const float cb0 = (1.0f - wb0) * kScale, cb1 = (1.0f - wb1) * kScale;
        const float p   = pv[k];
        const float mb0 = wb0 * p, mb1 = wb1 * p;
        sv[2 * k]     = fmaf(cb0, nB[k].x, mb0);
        sv[2 * k + 1] = fmaf(cb1, nB[k].y, mb1);
        mv[2 * k] = mb0; mv[2 * k + 1] = mb1;
        cv[2 * k] = cb0; cv[2 * k + 1] = cb1;
    }
    {
        f4_ a, b;
        a.x = sv[0]; a.y = sv[1]; a.z = sv[2]; a.w = sv[3];
        b.x = sv[4]; b.y = sv[5]; b.z = sv[6]; b.w = sv[7];
        *(f4u*)(sr + 8 * s)     = a;
        *(f4u*)(sr + 8 * s + 4) = b;
        a.x = mv[0]; a.y = mv[1]; a.z = mv[2]; a.w = mv[3];
        b.x = mv[4]; b.y = mv[5]; b.z = mv[6]; b.w = mv[7];
        *(f4u*)(mr + 8 * s)     = a;
        *(f4u*)(mr + 8 * s + 4) = b;
        a.x = cv[0]; a.y = cv[1]; a.z = cv[2]; a.w = cv[3];
        b.x = cv[4]; b.y = cv[5]; b.z = cv[6]; b.w = cv[7];
        *(f4u*)(cr + 8 * s)     = a;
        *(f4u*)(cr + 8 * s + 4) = b;
    }
}

extern "C" void kernel_launch(void* const* d_in, const int* in_sizes, int n_in,
                              void* d_out, int out_size, void* d_ws, size_t ws_size,
                              hipStream_t stream)
{
    const float* weights    = (const float*)d_in[0];
    const float* noise_root = (const float*)d_in[1];
    const float* noise_rest = (const float*)d_in[2];

    float* out     = (float*)d_out;
    float* samples = out;
    float* ms      = samples + (size_t)kRows * 4095;
    float* scales  = ms      + (size_t)kRows * 4094;

    lgt_top<<<kRows / 4, 256, 0, stream>>>(weights, noise_root, noise_rest,
                                           samples, ms, scales);
    lgt_bulk<<<kRows, 256, 0, stream>>>(weights, noise_rest,
                                        samples, ms, scales);
}